// Round 1
// baseline (1101.593 us; speedup 1.0000x reference)
//
#include <hip/hip_runtime.h>

#define S_LEN 2048
#define DHEAD 64
#define QBLK 32
#define KBLK 64
#define NTHR 512
#define BATCH 4
#define HEADS 16

typedef _Float16 half4v __attribute__((ext_vector_type(4)));
typedef _Float16 half8v __attribute__((ext_vector_type(8)));
typedef float floatx4 __attribute__((ext_vector_type(4)));

// Swizzles: XOR 16B-slot index with bits of the row so column-slice reads
// spread across banks (cdna_hip_programming.md G4 / T2).
__device__ __forceinline__ int swzK(int key, int b) { return b ^ ((key & 7) << 4); }
__device__ __forceinline__ int swzV(int key, int b) { return b ^ ((((key & 7) ^ ((key >> 3) & 3))) << 4); }
__device__ __forceinline__ int swzL(int r, int b) { return b ^ ((r & 7) << 4); }

__global__ __launch_bounds__(NTHR, 1)
void attn_fused(const float* __restrict__ qg, const float* __restrict__ kg,
                const float* __restrict__ vg, const int* __restrict__ maskg,
                float* __restrict__ outg, float* __restrict__ attng)
{
    __shared__ _Float16 lbuf[QBLK * S_LEN];      // 128 KB: logits, then p (f16)
    __shared__ _Float16 kvbuf[2][KBLK * DHEAD];  // 16 KB: K/V staging, double-buffered

    const int tid  = threadIdx.x;
    const int lane = tid & 63;
    const int w    = tid >> 6;   // wave 0..7
    const int wg   = w & 3;      // key/d column group
    const int wr   = w >> 2;     // row group (0/1)
    const int c    = lane & 15;  // col within 16
    const int g    = lane >> 4;  // 0..3

    const int nq = S_LEN / QBLK;             // 64 q-tiles per (b,h)
    const int bh = blockIdx.x / nq;
    const int qt = blockIdx.x % nq;
    const int b  = bh >> 4;                  // H = 16
    const int q0 = qt * QBLK;

    const float* qp = qg + (size_t)bh * S_LEN * DHEAD;
    const float* kp = kg + (size_t)bh * S_LEN * DHEAD;
    const float* vp = vg + (size_t)bh * S_LEN * DHEAD;
    const int*   mp = maskg + (size_t)b * S_LEN * S_LEN;
    float* outp  = outg  + (size_t)bh * S_LEN * DHEAD;
    float* attnp = attng + (size_t)bh * S_LEN * S_LEN;

    // ---- staging helper: 64 keys x 64 d, f32 global -> f16 LDS (swizzled) ----
    auto stage = [&](const float* base, int key0, int bufidx, bool isV) {
        _Float16* buf = &kvbuf[bufidx][0];
        #pragma unroll
        for (int p = 0; p < 2; ++p) {
            int f   = tid + p * NTHR;        // 0..1023 float4s
            int key = f >> 4;
            int d0  = (f & 15) << 2;
            float4 val = *(const float4*)(base + (size_t)(key0 + key) * DHEAD + d0);
            half4v h;
            h[0] = (_Float16)val.x; h[1] = (_Float16)val.y;
            h[2] = (_Float16)val.z; h[3] = (_Float16)val.w;
            int off = isV ? swzV(key, d0 * 2) : swzK(key, d0 * 2);
            *(half4v*)((char*)buf + key * 128 + off) = h;
        }
    };

    // ---- Q fragments, pre-scaled by 1/TEMPERATURE ----
    // A-frag layout: row = lane&15, k(d) = (lane>>4)*8 + j  (+32 for frag 1)
    half8v qf[2];
    {
        const float* src = qp + (size_t)(q0 + 16 * wr + c) * DHEAD + g * 8;
        #pragma unroll
        for (int f = 0; f < 2; ++f) {
            float4 a  = *(const float4*)(src + f * 32);
            float4 bb = *(const float4*)(src + f * 32 + 4);
            half8v h;
            h[0] = (_Float16)(a.x  * 0.125f); h[1] = (_Float16)(a.y  * 0.125f);
            h[2] = (_Float16)(a.z  * 0.125f); h[3] = (_Float16)(a.w  * 0.125f);
            h[4] = (_Float16)(bb.x * 0.125f); h[5] = (_Float16)(bb.y * 0.125f);
            h[6] = (_Float16)(bb.z * 0.125f); h[7] = (_Float16)(bb.w * 0.125f);
            qf[f] = h;
        }
    }

    // =========================== Phase A: QK^T ===========================
    stage(kp, 0, 0, false);
    __syncthreads();
    const int NT = S_LEN / KBLK; // 32
    for (int t = 0; t < NT; ++t) {
        if (t + 1 < NT) stage(kp, (t + 1) * KBLK, (t + 1) & 1, false);
        const char* kb = (const char*)&kvbuf[t & 1][0];
        int keyl = wg * 16 + c;
        // B-frag: col = key (lane&15 within group), k(d) = (lane>>4)*8+j
        half8v b0 = *(const half8v*)(kb + keyl * 128 + swzK(keyl, (g * 8) * 2));
        half8v b1 = *(const half8v*)(kb + keyl * 128 + swzK(keyl, (32 + g * 8) * 2));
        floatx4 acc = {0.f, 0.f, 0.f, 0.f};
        acc = __builtin_amdgcn_mfma_f32_16x16x32_f16(qf[0], b0, acc, 0, 0, 0);
        acc = __builtin_amdgcn_mfma_f32_16x16x32_f16(qf[1], b1, acc, 0, 0, 0);
        // C layout: col = lane&15, row = (lane>>4)*4 + i   (m89-verified)
        int key = t * KBLK + keyl;
        #pragma unroll
        for (int i = 0; i < 4; ++i) {
            int r = 16 * wr + g * 4 + i;
            *(_Float16*)((char*)lbuf + r * (S_LEN * 2) + swzL(r, key * 2)) = (_Float16)acc[i];
        }
        __syncthreads();
    }

    // ====================== Phase B: mask + softmax ======================
    // wave w owns rows 4w..4w+3; whole wave processes one row (2048 keys)
    #pragma unroll 1
    for (int rr = 0; rr < 4; ++rr) {
        int r    = w * 4 + rr;
        int grow = q0 + r;
        char* lrow = (char*)lbuf + r * (S_LEN * 2);
        const int* mrow = mp + (size_t)grow * S_LEN;
        float l[32];
        float m = -INFINITY;
        #pragma unroll
        for (int it = 0; it < 8; ++it) {
            int kk = it * 256 + lane * 4;
            half4v h = *(const half4v*)(lrow + swzL(r, kk * 2));
            int4 mk = *(const int4*)(mrow + kk);
            float x0 = mk.x ? (float)h[0] : -INFINITY;
            float x1 = mk.y ? (float)h[1] : -INFINITY;
            float x2 = mk.z ? (float)h[2] : -INFINITY;
            float x3 = mk.w ? (float)h[3] : -INFINITY;
            l[it * 4 + 0] = x0; l[it * 4 + 1] = x1;
            l[it * 4 + 2] = x2; l[it * 4 + 3] = x3;
            m = fmaxf(m, fmaxf(fmaxf(x0, x1), fmaxf(x2, x3)));
        }
        #pragma unroll
        for (int off = 32; off > 0; off >>= 1) m = fmaxf(m, __shfl_xor(m, off));
        float z = 0.f;
        #pragma unroll
        for (int i = 0; i < 32; ++i) { float e = __expf(l[i] - m); l[i] = e; z += e; }
        #pragma unroll
        for (int off = 32; off > 0; off >>= 1) z += __shfl_xor(z, off);
        float rz = 1.0f / z;
        float* arow = attnp + (size_t)grow * S_LEN;
        #pragma unroll
        for (int it = 0; it < 8; ++it) {
            int kk = it * 256 + lane * 4;
            float p0 = l[it * 4 + 0] * rz, p1 = l[it * 4 + 1] * rz;
            float p2 = l[it * 4 + 2] * rz, p3 = l[it * 4 + 3] * rz;
            float4 pv = {p0, p1, p2, p3};
            *(float4*)(arow + kk) = pv;                 // coalesced attn store
            half4v hp;
            hp[0] = (_Float16)p0; hp[1] = (_Float16)p1;
            hp[2] = (_Float16)p2; hp[3] = (_Float16)p3;
            *(half4v*)(lrow + swzL(r, kk * 2)) = hp;    // p back to LDS for PV
        }
    }
    __syncthreads();

    // ============================ Phase C: PV ============================
    floatx4 oacc = {0.f, 0.f, 0.f, 0.f};
    stage(vp, 0, 0, true);
    __syncthreads();
    for (int t = 0; t < NT; ++t) {
        if (t + 1 < NT) stage(vp, (t + 1) * KBLK, (t + 1) & 1, true);
        const char* vb = (const char*)&kvbuf[t & 1][0];
        // A-frag: P rows (this wave's 16 rows), 8 consecutive keys per lane
        int r = 16 * wr + c;
        const char* lrow = (const char*)lbuf + r * (S_LEN * 2);
        half8v a0 = *(const half8v*)(lrow + swzL(r, (t * 64 + g * 8) * 2));
        half8v a1 = *(const half8v*)(lrow + swzL(r, (t * 64 + 32 + g * 8) * 2));
        // B-frag: V[k][d], col = d (wg*16 + lane&15), k = (lane>>4)*8+j (strided gather)
        int dcol = wg * 16 + c;
        half8v b0, b1;
        #pragma unroll
        for (int j = 0; j < 8; ++j) {
            int kk0 = g * 8 + j;
            b0[j] = *(const _Float16*)(vb + kk0 * 128 + swzV(kk0, dcol * 2));
            int kk1 = 32 + g * 8 + j;
            b1[j] = *(const _Float16*)(vb + kk1 * 128 + swzV(kk1, dcol * 2));
        }
        oacc = __builtin_amdgcn_mfma_f32_16x16x32_f16(a0, b0, oacc, 0, 0, 0);
        oacc = __builtin_amdgcn_mfma_f32_16x16x32_f16(a1, b1, oacc, 0, 0, 0);
        __syncthreads();
    }
    {
        int dcol = wg * 16 + c;
        #pragma unroll
        for (int i = 0; i < 4; ++i) {
            int r = q0 + 16 * wr + g * 4 + i;
            outp[(size_t)r * DHEAD + dcol] = oacc[i];
        }
    }
}

extern "C" void kernel_launch(void* const* d_in, const int* in_sizes, int n_in,
                              void* d_out, int out_size, void* d_ws, size_t ws_size,
                              hipStream_t stream) {
    const float* q    = (const float*)d_in[0];
    const float* k    = (const float*)d_in[1];
    const float* v    = (const float*)d_in[2];
    const int*   mask = (const int*)d_in[3];
    float* out  = (float*)d_out;
    float* attn = out + (size_t)BATCH * HEADS * S_LEN * DHEAD;  // tuple: (out, attn)
    dim3 grid(BATCH * HEADS * (S_LEN / QBLK));
    attn_fused<<<grid, NTHR, 0, stream>>>(q, k, v, mask, out, attn);
}

// Round 2
// 855.040 us; speedup vs baseline: 1.2884x; 1.2884x over previous
//
#include <hip/hip_runtime.h>

#define S_LEN 2048
#define DHEAD 64
#define QBLK 16
#define KBLK 128
#define NTHR 512
#define BATCH 4
#define HEADS 16
#define NT (S_LEN / KBLK)   // 16 iterations per phase

typedef _Float16 half4v __attribute__((ext_vector_type(4)));
typedef _Float16 half8v __attribute__((ext_vector_type(8)));
typedef float floatx4 __attribute__((ext_vector_type(4)));

// XOR swizzles on 16B slots (G4/T2): spread strided column reads across banks.
__device__ __forceinline__ int swzK(int key, int b) { return b ^ ((key & 7) << 4); }
__device__ __forceinline__ int swzV(int key, int b) { return b ^ ((((key & 7) ^ ((key >> 3) & 3))) << 4); }
__device__ __forceinline__ int swzL(int r, int b) { return b ^ ((r & 7) << 4); }

__global__ __launch_bounds__(NTHR, 4)
void attn_fused(const float* __restrict__ qg, const float* __restrict__ kg,
                const float* __restrict__ vg, const int* __restrict__ maskg,
                float* __restrict__ outg, float* __restrict__ attng)
{
    __shared__ _Float16 lbuf[QBLK * S_LEN];     // 64 KB: logits, then p (f16)
    __shared__ _Float16 kvbuf[KBLK * DHEAD];    // 16 KB: K/V tile (single buf, reg-prefetched)
    // total 80 KB -> 2 blocks/CU

    const int tid  = threadIdx.x;
    const int lane = tid & 63;
    const int w    = tid >> 6;   // wave 0..7
    const int c    = lane & 15;
    const int g    = lane >> 4;  // 0..3

    const int nq = S_LEN / QBLK;             // 128 q-tiles per (b,h)
    const int bh = blockIdx.x / nq;
    const int qt = blockIdx.x % nq;
    const int b  = bh / HEADS;
    const int q0 = qt * QBLK;

    const float* qp = qg + (size_t)bh * S_LEN * DHEAD;
    const float* kp = kg + (size_t)bh * S_LEN * DHEAD;
    const float* vp = vg + (size_t)bh * S_LEN * DHEAD;
    const int*   mp = maskg + (size_t)b * S_LEN * S_LEN;
    float* outp  = outg  + (size_t)bh * S_LEN * DHEAD;
    float* attnp = attng + (size_t)bh * S_LEN * S_LEN;

    // ---- T14 staging: issue loads early (regs), convert+write LDS late ----
    float4 pre[4];
    auto loadKV = [&](const float* base, int key0) {
        #pragma unroll
        for (int p = 0; p < 4; ++p) {
            int f   = tid + p * NTHR;        // 0..2047 float4s (128 keys x 16 d-quads)
            int key = f >> 4;
            int d0  = (f & 15) << 2;
            pre[p] = *(const float4*)(base + (size_t)(key0 + key) * DHEAD + d0);
        }
    };
    auto writeKV = [&](bool isV) {
        #pragma unroll
        for (int p = 0; p < 4; ++p) {
            int f   = tid + p * NTHR;
            int key = f >> 4;
            int d0  = (f & 15) << 2;
            half4v h;
            h[0] = (_Float16)pre[p].x; h[1] = (_Float16)pre[p].y;
            h[2] = (_Float16)pre[p].z; h[3] = (_Float16)pre[p].w;
            int off = isV ? swzV(key, d0 * 2) : swzK(key, d0 * 2);
            *(half4v*)((char*)kvbuf + key * 128 + off) = h;
        }
    };

    // ---- Q fragments (rows q0..q0+15), pre-scaled by 1/TEMPERATURE ----
    // A-frag: row = lane&15, k(d) = (lane>>4)*8 + j  (+32 for frag 1)
    half8v qf[2];
    {
        const float* src = qp + (size_t)(q0 + c) * DHEAD + g * 8;
        #pragma unroll
        for (int f = 0; f < 2; ++f) {
            float4 a  = *(const float4*)(src + f * 32);
            float4 bb = *(const float4*)(src + f * 32 + 4);
            half8v h;
            h[0] = (_Float16)(a.x  * 0.125f); h[1] = (_Float16)(a.y  * 0.125f);
            h[2] = (_Float16)(a.z  * 0.125f); h[3] = (_Float16)(a.w  * 0.125f);
            h[4] = (_Float16)(bb.x * 0.125f); h[5] = (_Float16)(bb.y * 0.125f);
            h[6] = (_Float16)(bb.z * 0.125f); h[7] = (_Float16)(bb.w * 0.125f);
            qf[f] = h;
        }
    }

    // =========================== Phase A: QK^T ===========================
    loadKV(kp, 0);
    writeKV(false);
    __syncthreads();
    for (int t = 0; t < NT; ++t) {
        if (t + 1 < NT) loadKV(kp, (t + 1) * KBLK);   // issue early, consume late
        // wave w owns keys [w*16, w*16+16) of this 128-key tile
        int keyl = w * 16 + c;
        half8v b0 = *(const half8v*)((const char*)kvbuf + keyl * 128 + swzK(keyl, (g * 8) * 2));
        half8v b1 = *(const half8v*)((const char*)kvbuf + keyl * 128 + swzK(keyl, (32 + g * 8) * 2));
        floatx4 acc = {0.f, 0.f, 0.f, 0.f};
        acc = __builtin_amdgcn_mfma_f32_16x16x32_f16(qf[0], b0, acc, 0, 0, 0);
        acc = __builtin_amdgcn_mfma_f32_16x16x32_f16(qf[1], b1, acc, 0, 0, 0);
        // C layout: col = lane&15 (key), row = (lane>>4)*4 + i (q-row)
        int key = t * KBLK + keyl;
        #pragma unroll
        for (int i = 0; i < 4; ++i) {
            int r = g * 4 + i;
            *(_Float16*)((char*)lbuf + r * (S_LEN * 2) + swzL(r, key * 2)) = (_Float16)acc[i];
        }
        __syncthreads();                 // kvbuf reads done
        if (t + 1 < NT) writeKV(false);  // overwrite with next tile
        __syncthreads();                 // writes visible
    }

    // ====================== Phase B: mask + softmax ======================
    // wave w owns rows 2w, 2w+1; whole wave processes one row (2048 keys)
    #pragma unroll 1
    for (int rr = 0; rr < 2; ++rr) {
        int r    = w * 2 + rr;
        int grow = q0 + r;
        char* lrow = (char*)lbuf + r * (S_LEN * 2);
        const int* mrow = mp + (size_t)grow * S_LEN;
        float l[32];
        float m = -INFINITY;
        #pragma unroll
        for (int it = 0; it < 8; ++it) {
            int kk = it * 256 + lane * 4;
            half4v h = *(const half4v*)(lrow + swzL(r, kk * 2));
            int4 mk = *(const int4*)(mrow + kk);
            float x0 = mk.x ? (float)h[0] : -INFINITY;
            float x1 = mk.y ? (float)h[1] : -INFINITY;
            float x2 = mk.z ? (float)h[2] : -INFINITY;
            float x3 = mk.w ? (float)h[3] : -INFINITY;
            l[it * 4 + 0] = x0; l[it * 4 + 1] = x1;
            l[it * 4 + 2] = x2; l[it * 4 + 3] = x3;
            m = fmaxf(m, fmaxf(fmaxf(x0, x1), fmaxf(x2, x3)));
        }
        #pragma unroll
        for (int off = 32; off > 0; off >>= 1) m = fmaxf(m, __shfl_xor(m, off));
        float z = 0.f;
        #pragma unroll
        for (int i = 0; i < 32; ++i) { float e = __expf(l[i] - m); l[i] = e; z += e; }
        #pragma unroll
        for (int off = 32; off > 0; off >>= 1) z += __shfl_xor(z, off);
        float rz = 1.0f / z;
        float* arow = attnp + (size_t)grow * S_LEN;
        #pragma unroll
        for (int it = 0; it < 8; ++it) {
            int kk = it * 256 + lane * 4;
            float p0 = l[it * 4 + 0] * rz, p1 = l[it * 4 + 1] * rz;
            float p2 = l[it * 4 + 2] * rz, p3 = l[it * 4 + 3] * rz;
            float4 pv = {p0, p1, p2, p3};
            *(float4*)(arow + kk) = pv;                 // coalesced attn store
            half4v hp;
            hp[0] = (_Float16)p0; hp[1] = (_Float16)p1;
            hp[2] = (_Float16)p2; hp[3] = (_Float16)p3;
            *(half4v*)(lrow + swzL(r, kk * 2)) = hp;    // p back to LDS for PV
        }
    }
    __syncthreads();

    // ============================ Phase C: PV ============================
    // wave w: d-group wg = w&3 (cols wg*16..+15), key-half wk = w>>2 (64 keys/iter)
    const int wg = w & 3;
    const int wk = w >> 2;
    floatx4 oacc = {0.f, 0.f, 0.f, 0.f};
    loadKV(vp, 0);
    writeKV(true);
    __syncthreads();
    for (int t = 0; t < NT; ++t) {
        if (t + 1 < NT) loadKV(vp, (t + 1) * KBLK);
        // A-frag: p rows (all 16), 8 consecutive keys per lane
        const char* lrow = (const char*)lbuf + c * (S_LEN * 2);
        int kb0 = t * KBLK + wk * 64;
        half8v a0 = *(const half8v*)(lrow + swzL(c, (kb0 + g * 8) * 2));
        half8v a1 = *(const half8v*)(lrow + swzL(c, (kb0 + 32 + g * 8) * 2));
        // B-frag: V[k][d], col = d (wg*16 + c), k = g*8+j (strided gather, swzV spreads banks)
        int dcol = wg * 16 + c;
        half8v b0, b1;
        #pragma unroll
        for (int j = 0; j < 8; ++j) {
            int k0 = wk * 64 + g * 8 + j;
            b0[j] = *(const _Float16*)((const char*)kvbuf + k0 * 128 + swzV(k0, dcol * 2));
            int k1 = wk * 64 + 32 + g * 8 + j;
            b1[j] = *(const _Float16*)((const char*)kvbuf + k1 * 128 + swzV(k1, dcol * 2));
        }
        oacc = __builtin_amdgcn_mfma_f32_16x16x32_f16(a0, b0, oacc, 0, 0, 0);
        oacc = __builtin_amdgcn_mfma_f32_16x16x32_f16(a1, b1, oacc, 0, 0, 0);
        __syncthreads();
        if (t + 1 < NT) writeKV(true);
        __syncthreads();
    }
    // cross-wave key-half reduction (alias scratch onto kvbuf, now dead)
    float* rbuf = (float*)kvbuf;
    if (wk == 1) {
        #pragma unroll
        for (int i = 0; i < 4; ++i) {
            int r = g * 4 + i;
            rbuf[(wg * 16 + r) * 16 + c] = oacc[i];
        }
    }
    __syncthreads();
    if (wk == 0) {
        int dcol = wg * 16 + c;
        #pragma unroll
        for (int i = 0; i < 4; ++i) {
            int r = g * 4 + i;
            float val = oacc[i] + rbuf[(wg * 16 + r) * 16 + c];
            outp[(size_t)(q0 + r) * DHEAD + dcol] = val;
        }
    }
}

extern "C" void kernel_launch(void* const* d_in, const int* in_sizes, int n_in,
                              void* d_out, int out_size, void* d_ws, size_t ws_size,
                              hipStream_t stream) {
    const float* q    = (const float*)d_in[0];
    const float* k    = (const float*)d_in[1];
    const float* v    = (const float*)d_in[2];
    const int*   mask = (const int*)d_in[3];
    float* out  = (float*)d_out;
    float* attn = out + (size_t)BATCH * HEADS * S_LEN * DHEAD;  // tuple: (out, attn)
    dim3 grid(BATCH * HEADS * (S_LEN / QBLK));
    attn_fused<<<grid, NTHR, 0, stream>>>(q, k, v, mask, out, attn);
}